// Round 1
// baseline (3129.152 us; speedup 1.0000x reference)
//
#include <hip/hip_runtime.h>
#include <math.h>

#define BN_EPS 1e-5f

// Problem dims
constexpr int B  = 8;
constexpr int CG = 32, HG = 160, WG = 320;   // guidance
constexpr int C1 = 64, H  = 80,  W  = 160;   // x after conv1 (stride 2)
constexpr int TH = 8,  TW = 16;              // pixel tile per block

// ---------------------------------------------------------------------------
// Kernel A: conv1 (3x3, stride 2, pad 1) + BN + ReLU
//   guidance (B,32,160,320) -> x (B,64,80,160) f32 in d_ws
// ---------------------------------------------------------------------------
__global__ __launch_bounds__(256) void conv1_bn_relu(
    const float* __restrict__ g, const float* __restrict__ w1,
    const float* __restrict__ gamma, const float* __restrict__ beta,
    const float* __restrict__ mean, const float* __restrict__ var,
    float* __restrict__ xout)
{
    const int tx0 = blockIdx.x * TW;
    const int ty0 = blockIdx.y * TH;
    const int b   = blockIdx.z;

    __shared__ float gl[CG][2 * TH + 1][2 * TW + 1];   // 32 x 17 x 33 = 71.8 KB

    const int tid = threadIdx.x;
    constexpr int ROWS = 2 * TH + 1, COLS = 2 * TW + 1;
    constexpr int SLAB = CG * ROWS * COLS;
    for (int idx = tid; idx < SLAB; idx += 256) {
        int cin = idx / (ROWS * COLS);
        int rem = idx % (ROWS * COLS);
        int r = rem / COLS, c = rem % COLS;
        int gy = 2 * ty0 - 1 + r, gx = 2 * tx0 - 1 + c;
        float v = 0.f;
        if (gy >= 0 && gy < HG && gx >= 0 && gx < WG)
            v = g[((b * CG + cin) * HG + gy) * WG + gx];
        gl[cin][r][c] = v;
    }
    __syncthreads();

    const int p  = tid & 127;          // pixel within tile
    const int py = p / TW, px = p % TW;
    const int cog = __builtin_amdgcn_readfirstlane(tid >> 7);  // 0 or 1 (wave-uniform)

    float acc[32];
#pragma unroll
    for (int m = 0; m < 32; ++m) acc[m] = 0.f;

    for (int cin = 0; cin < CG; ++cin) {
        float xv[9];
#pragma unroll
        for (int t = 0; t < 9; ++t)
            xv[t] = gl[cin][2 * py + t / 3][2 * px + t % 3];
#pragma unroll
        for (int m = 0; m < 32; ++m) {
            const float* wp = w1 + ((cog * 32 + m) * CG + cin) * 9;
            float s = acc[m];
#pragma unroll
            for (int t = 0; t < 9; ++t) s = fmaf(xv[t], wp[t], s);
            acc[m] = s;
        }
    }

    const int y = ty0 + py, x = tx0 + px;
#pragma unroll
    for (int m = 0; m < 32; ++m) {
        int co = cog * 32 + m;
        float inv = rsqrtf(var[co] + BN_EPS);
        float v = (acc[m] - mean[co]) * (inv * gamma[co]) + beta[co];
        v = fmaxf(v, 0.f);
        xout[((b * C1 + co) * H + y) * W + x] = v;
    }
}

// ---------------------------------------------------------------------------
// Kernel B: conv2 (3x3, stride 1, pad 1, 64 -> 576) + softmax(9) + convex
//           combine with 3x3 unfold of 8*disp + pixel shuffle to (B,640,1280)
// ---------------------------------------------------------------------------
__global__ __launch_bounds__(256) void conv2_softmax_combine(
    const float* __restrict__ xin, const float* __restrict__ w2,
    const float* __restrict__ disp, float* __restrict__ out)
{
    const int tx0 = blockIdx.x * TW;
    const int ty0 = blockIdx.y * TH;
    const int b   = blockIdx.z;

    __shared__ float xl[C1][TH + 2][TW + 2];   // 64 x 10 x 18 = 46 KB
    __shared__ float d8[TH + 2][TW + 2];       // 8*disp tile (zero-padded)

    const int tid = threadIdx.x;
    constexpr int ROWS = TH + 2, COLS = TW + 2;
    constexpr int SLAB = C1 * ROWS * COLS;
    for (int idx = tid; idx < SLAB; idx += 256) {
        int cin = idx / (ROWS * COLS);
        int rem = idx % (ROWS * COLS);
        int r = rem / COLS, c = rem % COLS;
        int y = ty0 - 1 + r, x = tx0 - 1 + c;
        float v = 0.f;
        if (y >= 0 && y < H && x >= 0 && x < W)
            v = xin[((b * C1 + cin) * H + y) * W + x];
        xl[cin][r][c] = v;
    }
    for (int idx = tid; idx < ROWS * COLS; idx += 256) {
        int r = idx / COLS, c = idx % COLS;
        int y = ty0 - 1 + r, x = tx0 - 1 + c;
        float v = 0.f;
        if (y >= 0 && y < H && x >= 0 && x < W)
            v = 8.f * disp[(b * H + y) * W + x];
        d8[r][c] = v;
    }
    __syncthreads();

    const int p  = tid & 127;
    const int py = p / TW, px = p % TW;
    const int ijg = __builtin_amdgcn_readfirstlane(tid >> 7);  // 0 or 1
    const int y = ty0 + py, x = tx0 + px;

    float pat[9];
#pragma unroll
    for (int k = 0; k < 9; ++k) pat[k] = d8[py + k / 3][px + k % 3];

    // 32 (i,j) sub-positions per thread, chunks of 4 to bound registers
    for (int qc = 0; qc < 8; ++qc) {
        float logit[4][9];
#pragma unroll
        for (int qq = 0; qq < 4; ++qq)
#pragma unroll
            for (int k = 0; k < 9; ++k) logit[qq][k] = 0.f;

        for (int cin = 0; cin < C1; ++cin) {
            float xv[9];
#pragma unroll
            for (int t = 0; t < 9; ++t)
                xv[t] = xl[cin][py + t / 3][px + t % 3];
#pragma unroll
            for (int qq = 0; qq < 4; ++qq) {
                const int ij = ijg * 32 + qc * 4 + qq;
#pragma unroll
                for (int k = 0; k < 9; ++k) {
                    const float* wp = w2 + (((k * 64 + ij) * C1) + cin) * 9;
                    float s = logit[qq][k];
#pragma unroll
                    for (int t = 0; t < 9; ++t) s = fmaf(xv[t], wp[t], s);
                    logit[qq][k] = s;
                }
            }
        }

#pragma unroll
        for (int qq = 0; qq < 4; ++qq) {
            const int ij = ijg * 32 + qc * 4 + qq;
            float mx = logit[qq][0];
#pragma unroll
            for (int k = 1; k < 9; ++k) mx = fmaxf(mx, logit[qq][k]);
            float sum = 0.f, up = 0.f;
#pragma unroll
            for (int k = 0; k < 9; ++k) {
                float e = __expf(logit[qq][k] - mx);
                sum += e;
                up  += e * pat[k];
            }
            up /= sum;
            const int i = ij >> 3, j = ij & 7;
            out[((size_t)b * (8 * H) + (y * 8 + i)) * (size_t)(8 * W) + (x * 8 + j)] = up;
        }
    }
}

// ---------------------------------------------------------------------------
extern "C" void kernel_launch(void* const* d_in, const int* in_sizes, int n_in,
                              void* d_out, int out_size, void* d_ws, size_t ws_size,
                              hipStream_t stream)
{
    const float* guidance = (const float*)d_in[0];
    const float* disp     = (const float*)d_in[1];
    const float* conv1_w  = (const float*)d_in[2];
    const float* bn_gamma = (const float*)d_in[3];
    const float* bn_beta  = (const float*)d_in[4];
    const float* bn_mean  = (const float*)d_in[5];
    const float* bn_var   = (const float*)d_in[6];
    const float* conv2_w  = (const float*)d_in[7];
    float* out = (float*)d_out;
    float* x   = (float*)d_ws;   // B*64*80*160 f32 = 26.2 MB

    dim3 grid(W / TW, H / TH, B);   // (10, 10, 8)
    dim3 block(256);

    conv1_bn_relu<<<grid, block, 0, stream>>>(
        guidance, conv1_w, bn_gamma, bn_beta, bn_mean, bn_var, x);
    conv2_softmax_combine<<<grid, block, 0, stream>>>(
        x, conv2_w, disp, out);
}

// Round 2
// 194.501 us; speedup vs baseline: 16.0881x; 16.0881x over previous
//
#include <hip/hip_runtime.h>
#include <math.h>

typedef _Float16 half8 __attribute__((ext_vector_type(8)));
typedef float f32x4 __attribute__((ext_vector_type(4)));

// dims
constexpr int B_ = 8;
constexpr int HG = 160, WG = 320;          // guidance spatial
constexpr int H = 80, W = 160;             // x spatial
// ws layout (bytes)
constexpr size_t BWS_OFF  = 0;             // 18 * 36864 = 663552
constexpr size_t W1WS_OFF = 663552;        // 9 * 4096  = 36864
constexpr size_t XG_OFF   = 700416;        // 8*80*160*64*2 = 13107200

// swizzled position of (n, kl) within a 576x32 (or 64x32) f16 K-step block:
// paired-n 128B rows, 16B slots XOR-swizzled by (n>>1)&7 -> conflict-free b128 reads.
__device__ __host__ inline int swz_pos(int n, int kl) {
    return ((n >> 1) * 128) + 16 * ((((n & 1) << 2) + (kl >> 3)) ^ ((n >> 1) & 7)) + ((kl & 7) << 1);
}

// ---------------------------------------------------------------------------
// prep: w2 -> Bws [s=18][576n x 32kl swizzled], w1 -> w1ws [s=9][64ch x 32kl]
// K ordering: conv2 K = t*64 + cin  (step s: t=s>>1, c0=(s&1)*32)
//             conv1 K = t*32 + cin  (step s: t=s)
// ---------------------------------------------------------------------------
__global__ __launch_bounds__(256) void prep(const float* __restrict__ w1,
                                            const float* __restrict__ w2,
                                            char* __restrict__ ws)
{
    int e = blockIdx.x * 256 + threadIdx.x;
    if (e < 18 * 576 * 32) {
        int s = e / (576 * 32), rem = e % (576 * 32);
        int n = rem >> 5, kl = rem & 31;
        int cin = (s & 1) * 32 + kl, t = s >> 1;
        float v = w2[(n * 64 + cin) * 9 + t];
        *(_Float16*)(ws + BWS_OFF + (size_t)s * 36864 + swz_pos(n, kl)) = (_Float16)v;
    } else {
        int e2 = e - 18 * 576 * 32;
        if (e2 < 9 * 64 * 32) {
            int s = e2 / 2048, rem = e2 % 2048;
            int ch = rem >> 5, kl = rem & 31;
            float v = w1[(ch * 32 + kl) * 9 + s];
            *(_Float16*)(ws + W1WS_OFF + (size_t)s * 4096 + swz_pos(ch, kl)) = (_Float16)v;
        }
    }
}

// ---------------------------------------------------------------------------
// conv1 (3x3 s2 p1, 32->64) + BN + ReLU via MFMA. Output f16 NHWC.
// block: 256 thr = 4 waves (wm = wid&1 over pixels, wn = wid>>1 over channels)
// pixel tile 8x8, guidance window 17x17x32 (cin padded to 40 in LDS)
// ---------------------------------------------------------------------------
__global__ __launch_bounds__(256) void conv1_mfma(
    const float* __restrict__ g, const char* __restrict__ ws_w1,
    const float* __restrict__ gamma, const float* __restrict__ beta,
    const float* __restrict__ mean, const float* __restrict__ var,
    _Float16* __restrict__ xg)
{
    const int tx0 = blockIdx.x * 8, ty0 = blockIdx.y * 8, b = blockIdx.z;
    __shared__ __align__(16) _Float16 gl[17 * 17 * 40];   // 23120 B
    __shared__ __align__(16) _Float16 wlds[64 * 32];      // 4096 B
    const int tid = threadIdx.x;
    const _Float16* w1ws = (const _Float16*)ws_w1;

    for (int idx = tid; idx < 17 * 32 * 17; idx += 256) {
        int rr = idx / (32 * 17); int rem = idx - rr * (32 * 17);
        int cin = rem / 17, cc = rem - cin * 17;
        int gy = 2 * ty0 - 1 + rr, gx = 2 * tx0 - 1 + cc;
        float v = 0.f;
        if (gy >= 0 && gy < HG && gx >= 0 && gx < WG)
            v = g[((size_t)(b * 32 + cin) * HG + gy) * WG + gx];
        gl[(rr * 17 + cc) * 40 + cin] = (_Float16)v;
    }

    const int lane = tid & 63, wid = tid >> 6;
    const int wm = wid & 1, wn = wid >> 1;
    const int c = lane & 15, grp = lane >> 4;
    const int slot = ((((c & 1) << 2) + grp) ^ ((c >> 1) & 7));
    const int bbase = wn * 1024 + (c >> 1) * 64 + slot * 8;   // f16 units

    f32x4 zf = {0.f, 0.f, 0.f, 0.f};
    f32x4 acc[2][2];
    acc[0][0] = zf; acc[0][1] = zf; acc[1][0] = zf; acc[1][1] = zf;

    half8 stg = *(const half8*)(w1ws + tid * 8);   // step 0 prefetch

#pragma unroll
    for (int s = 0; s < 9; ++s) {
        __syncthreads();
        *(half8*)&wlds[tid * 8] = stg;
        __syncthreads();
        if (s < 8) stg = *(const half8*)(w1ws + (s + 1) * 2048 + tid * 8);
        const int dy = s / 3, dx = s - dy * 3;
        half8 af[2];
#pragma unroll
        for (int mt = 0; mt < 2; ++mt) {
            int rr = 2 * (wm * 4 + mt * 2 + (c >> 3)) + dy;
            int cc2 = 2 * (c & 7) + dx;
            af[mt] = *(const half8*)&gl[(rr * 17 + cc2) * 40 + grp * 8];
        }
#pragma unroll
        for (int nt = 0; nt < 2; ++nt) {
            half8 bf = *(const half8*)&wlds[nt * 512 + bbase];
            acc[0][nt] = __builtin_amdgcn_mfma_f32_16x16x32_f16(af[0], bf, acc[0][nt], 0, 0, 0);
            acc[1][nt] = __builtin_amdgcn_mfma_f32_16x16x32_f16(af[1], bf, acc[1][nt], 0, 0, 0);
        }
    }

#pragma unroll
    for (int nt = 0; nt < 2; ++nt) {
        int ch = wn * 32 + nt * 16 + c;
        float mu = mean[ch], scv = rsqrtf(var[ch] + 1e-5f) * gamma[ch], bt = beta[ch];
#pragma unroll
        for (int mt = 0; mt < 2; ++mt) {
#pragma unroll
            for (int r = 0; r < 4; ++r) {
                int p = wm * 32 + mt * 16 + grp * 4 + r;
                int y = ty0 + (p >> 3), xc = tx0 + (p & 7);
                float v = (acc[mt][nt][r] - mu) * scv + bt;
                v = fmaxf(v, 0.f);
                xg[(((size_t)(b * H + y) * W + xc) << 6) + ch] = (_Float16)v;
            }
        }
    }
}

// ---------------------------------------------------------------------------
// conv2 (3x3 s1 p1, 64->576) + softmax(9) + convex combine + pixel shuffle.
// block: 256 thr = 4 waves; each wave owns ij-set [wn*16, wn*16+16) for ALL
// 64 pixels (Mt=4) and all 9 k (n-tiles n = k*64 + wn*16 + c  -> k-complete
// per lane => lane-local softmax). K = t*64 + cin, 18 steps of 32.
// ---------------------------------------------------------------------------
__global__ __launch_bounds__(256) void conv2_mfma(
    const _Float16* __restrict__ xg, const char* __restrict__ ws_b,
    const float* __restrict__ disp, float* __restrict__ out)
{
    const int tx0 = blockIdx.x * 8, ty0 = blockIdx.y * 8, b = blockIdx.z;
    __shared__ __align__(16) _Float16 xs[100 * 72];   // 14400 B, rows padded 64->72
    __shared__ __align__(16) _Float16 wl[576 * 32];   // 36864 B, swizzled layout
    __shared__ float d8s[100];
    const int tid = threadIdx.x;
    const _Float16* Bws = (const _Float16*)ws_b;

    // stage x window 10x10x64 (f16), zero OOB
    half8 zero8;
#pragma unroll
    for (int j = 0; j < 8; ++j) zero8[j] = (_Float16)0.f;
#pragma unroll
    for (int i = 0; i < 4; ++i) {
        int cidx = i * 256 + tid;
        if (cidx < 800) {
            int wp = cidx >> 3, part = cidx & 7;
            int rr = wp / 10, cc = wp - rr * 10;
            int y = ty0 - 1 + rr, xc = tx0 - 1 + cc;
            half8 v = zero8;
            if (y >= 0 && y < H && xc >= 0 && xc < W)
                v = *(const half8*)(xg + (((size_t)(b * H + y) * W + xc) << 6) + part * 8);
            *(half8*)&xs[wp * 72 + part * 8] = v;
        }
    }
    if (tid < 100) {
        int rr = tid / 10, cc = tid - rr * 10;
        int y = ty0 - 1 + rr, xc = tx0 - 1 + cc;
        float v = 0.f;
        if (y >= 0 && y < H && xc >= 0 && xc < W) v = 8.f * disp[(b * H + y) * W + xc];
        d8s[tid] = v;
    }

    const int lane = tid & 63, wn = tid >> 6;
    const int c = lane & 15, grp = lane >> 4;
    const int slot = ((((c & 1) << 2) + grp) ^ ((c >> 1) & 7));
    const int bbase = wn * 512 + (c >> 1) * 64 + slot * 8;   // f16 units
    const int apr = c >> 3, apc = c & 7;

    f32x4 zf = {0.f, 0.f, 0.f, 0.f};
    f32x4 acc[4][9];
#pragma unroll
    for (int m = 0; m < 4; ++m) {
#pragma unroll
        for (int k = 0; k < 9; ++k) acc[m][k] = zf;
    }

    // prefetch weight step 0 into regs
    half8 stg[9];
#pragma unroll
    for (int i = 0; i < 9; ++i) stg[i] = *(const half8*)(Bws + (i * 256 + tid) * 8);

#pragma unroll
    for (int s = 0; s < 18; ++s) {
        __syncthreads();   // previous step's reads of wl done
#pragma unroll
        for (int i = 0; i < 9; ++i) *(half8*)&wl[(i * 256 + tid) * 8] = stg[i];
        __syncthreads();   // wl ready
        if (s < 17) {
#pragma unroll
            for (int i = 0; i < 9; ++i)
                stg[i] = *(const half8*)(Bws + (size_t)(s + 1) * 18432 + (i * 256 + tid) * 8);
        }
        const int t = s >> 1, c0 = (s & 1) * 32;
        const int dy = t / 3, dx = t - dy * 3;
        half8 af[4];
#pragma unroll
        for (int mt = 0; mt < 4; ++mt) {
            int rr = mt * 2 + apr + dy, cc2 = apc + dx;
            af[mt] = *(const half8*)&xs[(rr * 10 + cc2) * 72 + c0 + grp * 8];
        }
#pragma unroll
        for (int k = 0; k < 9; ++k) {
            half8 bf = *(const half8*)&wl[k * 2048 + bbase];
#pragma unroll
            for (int mt = 0; mt < 4; ++mt)
                acc[mt][k] = __builtin_amdgcn_mfma_f32_16x16x32_f16(af[mt], bf, acc[mt][k], 0, 0, 0);
        }
    }

    // epilogue: lane-local softmax over 9 k per (pixel, ij)
    const int ij = wn * 16 + c;
    const int oi = ij >> 3, oj = ij & 7;
#pragma unroll
    for (int mt = 0; mt < 4; ++mt) {
#pragma unroll
        for (int r = 0; r < 4; ++r) {
            int p = mt * 16 + grp * 4 + r;
            int pr = p >> 3, pc = p & 7;
            float pat[9];
#pragma unroll
            for (int k9 = 0; k9 < 9; ++k9) pat[k9] = d8s[(pr + k9 / 3) * 10 + pc + k9 % 3];
            float mx = acc[mt][0][r];
#pragma unroll
            for (int k9 = 1; k9 < 9; ++k9) mx = fmaxf(mx, acc[mt][k9][r]);
            float sum = 0.f, up = 0.f;
#pragma unroll
            for (int k9 = 0; k9 < 9; ++k9) {
                float e = __expf(acc[mt][k9][r] - mx);
                sum += e; up += e * pat[k9];
            }
            int y = ty0 + pr, xc = tx0 + pc;
            out[((size_t)(b * (8 * H) + y * 8 + oi)) * (size_t)(8 * W) + xc * 8 + oj] = up / sum;
        }
    }
}

// ---------------------------------------------------------------------------
extern "C" void kernel_launch(void* const* d_in, const int* in_sizes, int n_in,
                              void* d_out, int out_size, void* d_ws, size_t ws_size,
                              hipStream_t stream)
{
    const float* guidance = (const float*)d_in[0];
    const float* disp     = (const float*)d_in[1];
    const float* conv1_w  = (const float*)d_in[2];
    const float* bn_gamma = (const float*)d_in[3];
    const float* bn_beta  = (const float*)d_in[4];
    const float* bn_mean  = (const float*)d_in[5];
    const float* bn_var   = (const float*)d_in[6];
    const float* conv2_w  = (const float*)d_in[7];
    float* out = (float*)d_out;
    char* ws = (char*)d_ws;
    _Float16* xg = (_Float16*)(ws + XG_OFF);

    prep<<<dim3((18 * 576 * 32 + 9 * 64 * 32 + 255) / 256), dim3(256), 0, stream>>>(
        conv1_w, conv2_w, ws);
    dim3 grid(W / 8, H / 8, B_);   // (20, 10, 8)
    conv1_mfma<<<grid, dim3(256), 0, stream>>>(
        guidance, ws + W1WS_OFF, bn_gamma, bn_beta, bn_mean, bn_var, xg);
    conv2_mfma<<<grid, dim3(256), 0, stream>>>(
        xg, ws + BWS_OFF, disp, out);
}

// Round 3
// 147.056 us; speedup vs baseline: 21.2787x; 1.3226x over previous
//
#include <hip/hip_runtime.h>
#include <math.h>

typedef _Float16 half8 __attribute__((ext_vector_type(8)));
typedef float f32x4 __attribute__((ext_vector_type(4)));

// dims
constexpr int B_ = 8;
constexpr int HG = 160, WG = 320;          // guidance spatial
constexpr int H = 80, W = 160;             // x spatial
// ws layout (bytes)
constexpr size_t BWS_OFF  = 0;             // 18 * 36864 = 663552
constexpr size_t W1WS_OFF = 663552;        // 9 * 4096  = 36864
constexpr size_t XG_OFF   = 700416;        // 8*80*160*64*2 = 13107200

// swizzled position of (n, kl) within a 576x32 (or 64x32) f16 K-step block:
// paired-n 128B rows, 16B slots XOR-swizzled by (n>>1)&7 -> conflict-free b128 reads.
__device__ __host__ inline int swz_pos(int n, int kl) {
    return ((n >> 1) * 128) + 16 * ((((n & 1) << 2) + (kl >> 3)) ^ ((n >> 1) & 7)) + ((kl & 7) << 1);
}

__device__ inline void gload_lds16(const void* g, void* l) {
    __builtin_amdgcn_global_load_lds(
        (const __attribute__((address_space(1))) void*)g,
        (__attribute__((address_space(3))) void*)l, 16, 0, 0);
}

// ---------------------------------------------------------------------------
// prep: w2 -> Bws [s=18][576n x 32kl swizzled], w1 -> w1ws [s=9][64ch x 32kl]
// K ordering: conv2 K = t*64 + cin  (step s: t=s>>1, c0=(s&1)*32)
//             conv1 K = t*32 + cin  (step s: t=s)
// ---------------------------------------------------------------------------
__global__ __launch_bounds__(256) void prep(const float* __restrict__ w1,
                                            const float* __restrict__ w2,
                                            char* __restrict__ ws)
{
    int e = blockIdx.x * 256 + threadIdx.x;
    if (e < 18 * 576 * 32) {
        int s = e / (576 * 32), rem = e % (576 * 32);
        int n = rem >> 5, kl = rem & 31;
        int cin = (s & 1) * 32 + kl, t = s >> 1;
        float v = w2[(n * 64 + cin) * 9 + t];
        *(_Float16*)(ws + BWS_OFF + (size_t)s * 36864 + swz_pos(n, kl)) = (_Float16)v;
    } else {
        int e2 = e - 18 * 576 * 32;
        if (e2 < 9 * 64 * 32) {
            int s = e2 / 2048, rem = e2 % 2048;
            int ch = rem >> 5, kl = rem & 31;
            float v = w1[(ch * 32 + kl) * 9 + s];
            *(_Float16*)(ws + W1WS_OFF + (size_t)s * 4096 + swz_pos(ch, kl)) = (_Float16)v;
        }
    }
}

// ---------------------------------------------------------------------------
// conv1 (3x3 s2 p1, 32->64) + BN + ReLU via MFMA. Output f16 NHWC.
// (unchanged from R2 — passed; tuning deferred)
// ---------------------------------------------------------------------------
__global__ __launch_bounds__(256) void conv1_mfma(
    const float* __restrict__ g, const char* __restrict__ ws_w1,
    const float* __restrict__ gamma, const float* __restrict__ beta,
    const float* __restrict__ mean, const float* __restrict__ var,
    _Float16* __restrict__ xg)
{
    const int tx0 = blockIdx.x * 8, ty0 = blockIdx.y * 8, b = blockIdx.z;
    __shared__ __align__(16) _Float16 gl[17 * 17 * 40];   // 23120 B
    __shared__ __align__(16) _Float16 wlds[64 * 32];      // 4096 B
    const int tid = threadIdx.x;
    const _Float16* w1ws = (const _Float16*)ws_w1;

    for (int idx = tid; idx < 17 * 32 * 17; idx += 256) {
        int rr = idx / (32 * 17); int rem = idx - rr * (32 * 17);
        int cin = rem / 17, cc = rem - cin * 17;
        int gy = 2 * ty0 - 1 + rr, gx = 2 * tx0 - 1 + cc;
        float v = 0.f;
        if (gy >= 0 && gy < HG && gx >= 0 && gx < WG)
            v = g[((size_t)(b * 32 + cin) * HG + gy) * WG + gx];
        gl[(rr * 17 + cc) * 40 + cin] = (_Float16)v;
    }

    const int lane = tid & 63, wid = tid >> 6;
    const int wm = wid & 1, wn = wid >> 1;
    const int c = lane & 15, grp = lane >> 4;
    const int slot = ((((c & 1) << 2) + grp) ^ ((c >> 1) & 7));
    const int bbase = wn * 1024 + (c >> 1) * 64 + slot * 8;   // f16 units

    f32x4 zf = {0.f, 0.f, 0.f, 0.f};
    f32x4 acc[2][2];
    acc[0][0] = zf; acc[0][1] = zf; acc[1][0] = zf; acc[1][1] = zf;

    half8 stg = *(const half8*)(w1ws + tid * 8);   // step 0 prefetch

#pragma unroll
    for (int s = 0; s < 9; ++s) {
        __syncthreads();
        *(half8*)&wlds[tid * 8] = stg;
        __syncthreads();
        if (s < 8) stg = *(const half8*)(w1ws + (s + 1) * 2048 + tid * 8);
        const int dy = s / 3, dx = s - dy * 3;
        half8 af[2];
#pragma unroll
        for (int mt = 0; mt < 2; ++mt) {
            int rr = 2 * (wm * 4 + mt * 2 + (c >> 3)) + dy;
            int cc2 = 2 * (c & 7) + dx;
            af[mt] = *(const half8*)&gl[(rr * 17 + cc2) * 40 + grp * 8];
        }
#pragma unroll
        for (int nt = 0; nt < 2; ++nt) {
            half8 bf = *(const half8*)&wlds[nt * 512 + bbase];
            acc[0][nt] = __builtin_amdgcn_mfma_f32_16x16x32_f16(af[0], bf, acc[0][nt], 0, 0, 0);
            acc[1][nt] = __builtin_amdgcn_mfma_f32_16x16x32_f16(af[1], bf, acc[1][nt], 0, 0, 0);
        }
    }

#pragma unroll
    for (int nt = 0; nt < 2; ++nt) {
        int ch = wn * 32 + nt * 16 + c;
        float mu = mean[ch], scv = rsqrtf(var[ch] + 1e-5f) * gamma[ch], bt = beta[ch];
#pragma unroll
        for (int mt = 0; mt < 2; ++mt) {
#pragma unroll
            for (int r = 0; r < 4; ++r) {
                int p = wm * 32 + mt * 16 + grp * 4 + r;
                int y = ty0 + (p >> 3), xc = tx0 + (p & 7);
                float v = (acc[mt][nt][r] - mu) * scv + bt;
                v = fmaxf(v, 0.f);
                xg[(((size_t)(b * H + y) * W + xc) << 6) + ch] = (_Float16)v;
            }
        }
    }
}

// ---------------------------------------------------------------------------
// conv2 (3x3 s1 p1, 64->576) + softmax(9) + convex combine + pixel shuffle.
// 512 thr = 8 waves: ng = wid&3 (16-ij set, k-complete per lane), mg = wid>>2
// (pixel half). Tile 16x8 = 128 pixels. Weights DMA'd via global_load_lds
// (double-buffered, 1 barrier/step). xs XOR-swizzled (slot ^= wp&7).
// ---------------------------------------------------------------------------
__global__ __launch_bounds__(512, 2) void conv2_mfma(
    const _Float16* __restrict__ xg, const char* __restrict__ ws_b,
    const float* __restrict__ disp, float* __restrict__ out)
{
    const int tx0 = blockIdx.x * 16, ty0 = blockIdx.y * 8, b = blockIdx.z;
    __shared__ __align__(16) _Float16 xs[180 * 64];       // 10r x 18c x 64ch, 23040 B
    __shared__ __align__(16) _Float16 wl[2][576 * 32];    // 73728 B (dbuf)
    __shared__ float d8s[180];
    const int tid = threadIdx.x;
    const int lane = tid & 63, wid = tid >> 6;

    // stage x window 10x18x64 f16, swizzled: 16B slot' = slot ^ (wp&7)
    half8 zero8;
#pragma unroll
    for (int j = 0; j < 8; ++j) zero8[j] = (_Float16)0.f;
    for (int cidx = tid; cidx < 1440; cidx += 512) {
        int wp = cidx >> 3, slot = cidx & 7;
        int rr = wp / 18, cc = wp - rr * 18;
        int y = ty0 - 1 + rr, xc = tx0 - 1 + cc;
        half8 v = zero8;
        if (y >= 0 && y < H && xc >= 0 && xc < W)
            v = *(const half8*)(xg + (((size_t)(b * H + y) * W + xc) << 6) + slot * 8);
        int slotp = slot ^ (wp & 7);
        *(half8*)&xs[wp * 64 + slotp * 8] = v;
    }
    if (tid < 180) {
        int rr = tid / 18, cc = tid - rr * 18;
        int y = ty0 - 1 + rr, xc = tx0 - 1 + cc;
        float v = 0.f;
        if (y >= 0 && y < H && xc >= 0 && xc < W) v = 8.f * disp[(b * H + y) * W + xc];
        d8s[tid] = v;
    }

    // DMA staging of one 36864B weight step-block (36 chunks of 1024B)
    auto stage = [&](int s, int buf) {
        const char* src = ws_b + (size_t)s * 36864;
        char* dst = (char*)&wl[buf][0];
        for (int ch = wid; ch < 36; ch += 8)
            gload_lds16(src + ch * 1024 + lane * 16, dst + ch * 1024 + lane * 16);
    };

    const int ng = wid & 3, mg = wid >> 2;
    const int c = lane & 15, grp = lane >> 4;
    const int slot_b = ((((c & 1) << 2) + grp) ^ ((c >> 1) & 7));
    const int bbase = ng * 512 + (c >> 1) * 64 + slot_b * 8;   // f16 units

    f32x4 zf = {0.f, 0.f, 0.f, 0.f};
    f32x4 acc[4][9];
#pragma unroll
    for (int m = 0; m < 4; ++m)
#pragma unroll
        for (int k = 0; k < 9; ++k) acc[m][k] = zf;

    stage(0, 0);
    __syncthreads();   // xs, d8s, wl[0] ready

#pragma unroll 2
    for (int s = 0; s < 18; ++s) {
        const int buf = s & 1;
        if (s < 17) stage(s + 1, buf ^ 1);   // overlaps with compute below

        const int t = s >> 1;
        const int dy = t / 3, dx = t - dy * 3;
        const int aslot = (s & 1) * 4 + grp;          // channel 16B-slot index
        half8 af[4];
#pragma unroll
        for (int mt = 0; mt < 4; ++mt) {
            int wp = (mg * 4 + mt + dy) * 18 + c + dx;
            af[mt] = *(const half8*)&xs[wp * 64 + (aslot ^ (wp & 7)) * 8];
        }
#pragma unroll
        for (int k = 0; k < 9; ++k) {
            half8 bf = *(const half8*)&wl[buf][k * 2048 + bbase];
#pragma unroll
            for (int mt = 0; mt < 4; ++mt)
                acc[mt][k] = __builtin_amdgcn_mfma_f32_16x16x32_f16(af[mt], bf, acc[mt][k], 0, 0, 0);
        }
        __syncthreads();   // drains DMA(s+1); wl[buf] reads done before overwrite
    }

    // epilogue: lane-local softmax over 9 k per (pixel, ij)
    const int ij = ng * 16 + c;
    const int oi = ij >> 3, oj = ij & 7;
#pragma unroll
    for (int mt = 0; mt < 4; ++mt) {
#pragma unroll
        for (int r = 0; r < 4; ++r) {
            int pr = mg * 4 + mt, pc = grp * 4 + r;
            float pat[9];
#pragma unroll
            for (int k9 = 0; k9 < 9; ++k9) pat[k9] = d8s[(pr + k9 / 3) * 18 + pc + k9 % 3];
            float mx = acc[mt][0][r];
#pragma unroll
            for (int k9 = 1; k9 < 9; ++k9) mx = fmaxf(mx, acc[mt][k9][r]);
            float sum = 0.f, up = 0.f;
#pragma unroll
            for (int k9 = 0; k9 < 9; ++k9) {
                float e = __expf(acc[mt][k9][r] - mx);
                sum += e; up += e * pat[k9];
            }
            int y = ty0 + pr, xc = tx0 + pc;
            out[((size_t)(b * (8 * H) + y * 8 + oi)) * (size_t)(8 * W) + xc * 8 + oj] = up / sum;
        }
    }
}

// ---------------------------------------------------------------------------
extern "C" void kernel_launch(void* const* d_in, const int* in_sizes, int n_in,
                              void* d_out, int out_size, void* d_ws, size_t ws_size,
                              hipStream_t stream)
{
    const float* guidance = (const float*)d_in[0];
    const float* disp     = (const float*)d_in[1];
    const float* conv1_w  = (const float*)d_in[2];
    const float* bn_gamma = (const float*)d_in[3];
    const float* bn_beta  = (const float*)d_in[4];
    const float* bn_mean  = (const float*)d_in[5];
    const float* bn_var   = (const float*)d_in[6];
    const float* conv2_w  = (const float*)d_in[7];
    float* out = (float*)d_out;
    char* ws = (char*)d_ws;
    _Float16* xg = (_Float16*)(ws + XG_OFF);

    prep<<<dim3((18 * 576 * 32 + 9 * 64 * 32 + 255) / 256), dim3(256), 0, stream>>>(
        conv1_w, conv2_w, ws);
    dim3 grid1(W / 8, H / 8, B_);    // (20, 10, 8)
    conv1_mfma<<<grid1, dim3(256), 0, stream>>>(
        guidance, ws + W1WS_OFF, bn_gamma, bn_beta, bn_mean, bn_var, xg);
    dim3 grid2(W / 16, H / 8, B_);   // (10, 10, 8)
    conv2_mfma<<<grid2, dim3(512), 0, stream>>>(
        xg, ws + BWS_OFF, disp, out);
}